// Round 10
// baseline (521.207 us; speedup 1.0000x reference)
//
#include <hip/hip_runtime.h>
#include <math.h>

#define NN 10000       // N_NODES
#define NE 160000      // N_EDGES
#define NG 100         // N_GRAPHS
#define DD 32
#define QQ 96
#define EPS 1e-5f

// ---------------- fused BN stats for BOTH convs' edge-MLPs (R9 version, kept).
__global__ __launch_bounds__(512) void k_stats4(const float* __restrict__ ea,
        const float* __restrict__ w1, const float* __restrict__ b1,
        const float* __restrict__ w2, const float* __restrict__ b2,
        float* __restrict__ stats) {
    __shared__ float eas[1536];   // 256 edges x 6 attrs
    const int tid = threadIdx.x;
    const int chunk = blockIdx.x >> 1;
    const int ct = ((blockIdx.x & 1) << 9) | tid;   // column 0..1023
    const float* wr1 = w1 + ct * 6;
    const float* wr2 = w2 + ct * 6;
    float2 W0 = make_float2(wr1[0], wr2[0]);
    float2 W1 = make_float2(wr1[1], wr2[1]);
    float2 W2 = make_float2(wr1[2], wr2[2]);
    float2 W3 = make_float2(wr1[3], wr2[3]);
    float2 W4 = make_float2(wr1[4], wr2[4]);
    float2 W5 = make_float2(wr1[5], wr2[5]);
    float2 Bb = make_float2(b1[ct], b2[ct]);
    float2 S = make_float2(0.f, 0.f), SS = make_float2(0.f, 0.f);
    const int base = chunk * 1536;
    eas[tid]        = ea[base + tid];
    eas[tid + 512]  = ea[base + tid + 512];
    eas[tid + 1024] = ea[base + tid + 1024];
    __syncthreads();
#pragma unroll 4
    for (int el = 0; el < 256; ++el) {
        const float* ep = &eas[el * 6];           // wave-uniform -> broadcast
        float2 p0 = *reinterpret_cast<const float2*>(ep);
        float2 p1 = *reinterpret_cast<const float2*>(ep + 2);
        float2 p2 = *reinterpret_cast<const float2*>(ep + 4);
        float2 y = Bb;
        y.x = fmaf(p0.x, W0.x, y.x); y.y = fmaf(p0.x, W0.y, y.y);
        y.x = fmaf(p0.y, W1.x, y.x); y.y = fmaf(p0.y, W1.y, y.y);
        y.x = fmaf(p1.x, W2.x, y.x); y.y = fmaf(p1.x, W2.y, y.y);
        y.x = fmaf(p1.y, W3.x, y.x); y.y = fmaf(p1.y, W3.y, y.y);
        y.x = fmaf(p2.x, W4.x, y.x); y.y = fmaf(p2.x, W4.y, y.y);
        y.x = fmaf(p2.y, W5.x, y.x); y.y = fmaf(p2.y, W5.y, y.y);
        float rx = fmaxf(y.x, 0.f), ry = fmaxf(y.y, 0.f);
        S.x += rx; S.y += ry;
        SS.x = fmaf(rx, rx, SS.x); SS.y = fmaf(ry, ry, SS.y);
    }
    atomicAdd(&stats[ct], S.x);
    atomicAdd(&stats[1024 + ct], SS.x);
    atomicAdd(&stats[2048 + ct], S.y);
    atomicAdd(&stats[3072 + ct], SS.y);
}

// -------- k_root: out[n,o] = bias[o] + x[n]@root.  Block gridDim-1 (optional,
// when doFin!=0) instead computes BOTH convs' BN affines from stats.
__global__ __launch_bounds__(256) void k_root(const float* __restrict__ x,
        const float* __restrict__ root, const float* __restrict__ bias,
        float* __restrict__ out,
        int doFin, const float* __restrict__ stats,
        const float* __restrict__ g1, const float* __restrict__ beta1,
        const float* __restrict__ g2, const float* __restrict__ beta2,
        float* __restrict__ AB) {
    const int tid = threadIdx.x;
    if (doFin && blockIdx.x == gridDim.x - 1) {
        const float invE = 1.f / NE;
        for (int j = tid; j < 2048; j += 256) {
            int cv = j >> 10, col = j & 1023;
            const float* st = stats + cv * 2048;
            const float* g = cv ? g2 : g1;
            const float* bt = cv ? beta2 : beta1;
            float mean = st[col] * invE;
            float var = fmaxf(st[1024 + col] * invE - mean * mean, 0.f);
            float a = g[col] * rsqrtf(var + EPS);
            AB[cv * 2048 + col] = a;
            AB[cv * 2048 + 1024 + col] = bt[col] - mean * a;
        }
        return;
    }
    __shared__ float rlds[1024];
#pragma unroll
    for (int r = 0; r < 4; ++r) rlds[tid + 256 * r] = root[tid + 256 * r];
    __syncthreads();
    const int o = tid & 31;
    const int gg = tid >> 5;
    const int n = blockIdx.x * 8 + gg;
    if (n >= NN) return;
    const int half = tid & 32;
    float xs = x[n * 32 + o];
    float acc = bias[o];
#pragma unroll
    for (int i = 0; i < 32; ++i) {
        float xi = __shfl(xs, half | i);
        acc = fmaf(xi, rlds[i * 32 + o], acc);
    }
    out[n * 32 + o] = acc;
}

// ------------- NNConv v3: 512-thread / 8-wave blocks; wave g covers i = g*4+{0..3};
// 2 cols/lane = 18 pinned invariants (under the ~24-28 spill cap seen R3-R9).
// Edge loop unrolled x2 with independent msg0/msg1 + separate atomics to break
// the per-iteration WAR->vmcnt chain on the atomic's data register.
#define CDECL(K) float w##K##0, w##K##1, w##K##2, w##K##3, w##K##4, w##K##5, bs##K, av##K, bv##K;
#define CLOAD(K) { const int _j = (((g << 2) + (K << 1) + p) << 5) | o; \
    const float* _wr = nw + _j * 6; \
    w##K##0 = _wr[0]; w##K##1 = _wr[1]; w##K##2 = _wr[2]; \
    w##K##3 = _wr[3]; w##K##4 = _wr[4]; w##K##5 = _wr[5]; \
    bs##K = nb[_j]; av##K = A[_j]; bv##K = B[_j]; }
#define CPIN(K) asm("" : "+v"(w##K##0), "+v"(w##K##1), "+v"(w##K##2), "+v"(w##K##3), \
                         "+v"(w##K##4), "+v"(w##K##5), "+v"(bs##K), "+v"(av##K), "+v"(bv##K));
#define CACC(K, XK, M) { float _y = bs##K; \
    _y = fmaf(e0, w##K##0, _y); _y = fmaf(e1, w##K##1, _y); _y = fmaf(e2, w##K##2, _y); \
    _y = fmaf(e3, w##K##3, _y); _y = fmaf(e4, w##K##4, _y); _y = fmaf(e5, w##K##5, _y); \
    float _t = fmaf(av##K, fmaxf(_y, 0.f), bv##K); M = fmaf(XK, _t, M); }

__global__ __launch_bounds__(512) void k_conv(const float* __restrict__ xin,
        const float* __restrict__ ea, const int* __restrict__ src, const int* __restrict__ dst,
        const float* __restrict__ nw, const float* __restrict__ nb,
        const float* __restrict__ A, const float* __restrict__ B,
        float* __restrict__ agg) {
    const int tid = threadIdx.x;
    const int lane = tid & 63;
    const int g = tid >> 6;        // wave = i-octant (i = g*4 .. g*4+3)
    const int p = lane >> 5;
    const int o = lane & 31;

    CDECL(0) CDECL(1)
    CLOAD(0) CLOAD(1)
    CPIN(0) CPIN(1)

    const int gs = gridDim.x;
    for (int e = blockIdx.x; e < NE; e += gs * 2) {
        {
            const int sc = src[e];                 // block-uniform -> s_load
            const int dc = dst[e];
            const float* er = ea + e * 6;
            float e0 = er[0], e1 = er[1], e2 = er[2], e3 = er[3], e4 = er[4], e5 = er[5];
            float4 q = *reinterpret_cast<const float4*>(xin + sc * 32 + (g << 2));
            float xA = p ? q.y : q.x;
            float xB = p ? q.w : q.z;
            float msg0 = 0.f;
            CACC(0, xA, msg0) CACC(1, xB, msg0)
            msg0 += __shfl_xor(msg0, 32, 64);
            if (p == 0) atomicAdd(&agg[dc * 32 + o], msg0);
        }
        const int e2 = e + gs;
        if (e2 < NE) {
            const int sc = src[e2];
            const int dc = dst[e2];
            const float* er = ea + e2 * 6;
            float e0 = er[0], e1 = er[1], e2v = er[2], e3 = er[3], e4 = er[4], e5 = er[5];
            float e2_ = e2v;
            float4 q = *reinterpret_cast<const float4*>(xin + sc * 32 + (g << 2));
            float xA = p ? q.y : q.x;
            float xB = p ? q.w : q.z;
            float msg1 = 0.f;
            {
                float e2 = e2_;   // shadow back for macro
                CACC(0, xA, msg1) CACC(1, xB, msg1)
            }
            msg1 += __shfl_xor(msg1, 32, 64);
            if (p == 0) atomicAdd(&agg[dc * 32 + o], msg1);
        }
    }
}

// ---------------------------------------- lin1: relu(cat(x1,x2)@W^T+b) + stats
__global__ __launch_bounds__(384) void k_lin1a(const float* __restrict__ x1,
        const float* __restrict__ x2, const float* __restrict__ lw, const float* __restrict__ lb,
        float* __restrict__ pre, float* __restrict__ gsum, float* __restrict__ gsumsq) {
    __shared__ float cat[4][64];
    __shared__ float sh_s[96], sh_ss[96];
    const int tid = threadIdx.x;
    const int np = tid / 96;   // 0..3
    const int q = tid - np * 96;
    float w[64];
#pragma unroll
    for (int k = 0; k < 64; ++k) w[k] = lw[q * 64 + k];
    const float bq = lb[q];
    float s = 0.f, ss = 0.f;
    for (int nb = blockIdx.x * 4; nb < NN; nb += gridDim.x * 4) {
        __syncthreads();
        if (tid < 256) {
            int n2 = tid >> 6, k = tid & 63;
            cat[n2][k] = (k < 32) ? x1[(nb + n2) * 32 + k] : x2[(nb + n2) * 32 + (k - 32)];
        }
        __syncthreads();
        float v = bq;
#pragma unroll
        for (int k = 0; k < 64; ++k) v = fmaf(cat[np][k], w[k], v);
        float r = fmaxf(v, 0.f);
        pre[(nb + np) * 96 + q] = r;
        s += r; ss = fmaf(r, r, ss);
    }
    __syncthreads();
    if (tid < 96) { sh_s[tid] = 0.f; sh_ss[tid] = 0.f; }
    __syncthreads();
    atomicAdd(&sh_s[q], s);
    atomicAdd(&sh_ss[q], ss);
    __syncthreads();
    if (tid < 96) {
        atomicAdd(&gsum[tid], sh_s[tid]);
        atomicAdd(&gsumsq[tid], sh_ss[tid]);
    }
}

__global__ __launch_bounds__(384) void k_lin1b(const float* __restrict__ gsum,
        const float* __restrict__ gsumsq, const float* __restrict__ g, const float* __restrict__ beta,
        const float* __restrict__ pre, float* __restrict__ xc) {
    const int tid = threadIdx.x;
    const int np = tid / 96;
    const int q = tid - np * 96;
    const float invN = 1.f / NN;
    float mean = gsum[q] * invN;
    float var = fmaxf(gsumsq[q] * invN - mean * mean, 0.f);
    float a = g[q] * rsqrtf(var + EPS);
    float b = beta[q] - mean * a;
    for (int nb = blockIdx.x * 4; nb < NN; nb += gridDim.x * 4) {
        int n = nb + np;
        xc[n * 96 + q] = fmaf(a, pre[n * 96 + q], b);
    }
}

// ------------------------------------------------- Set2Set: whole loop per graph
__global__ __launch_bounds__(512) void k_s2s(const float* __restrict__ xc,
        const int* __restrict__ batch,
        const float* __restrict__ w_ih, const float* __restrict__ w_hh,
        const float* __restrict__ b_ih, const float* __restrict__ b_hh,
        float* __restrict__ qs_g, float* __restrict__ e_ws) {
    __shared__ float qs[192], h[96], c[96], gates[384];
    __shared__ float redm[8], reds[8];
    __shared__ float racc_s[5][96];
    __shared__ float sh_scal[2];   // [0]=emax, [1]=1/asum
    __shared__ int sse[2];
    const int tid = threadIdx.x;
    const int wid = tid >> 6, lane = tid & 63;
    const int b = blockIdx.x;
    if (tid < 2) {   // inline graph-range binary search (start of graph b+tid)
        int key = b + tid, lo = 0, hi = NN;
        while (lo < hi) { int mid = (lo + hi) >> 1; if (batch[mid] < key) lo = mid + 1; else hi = mid; }
        sse[tid] = lo;
    }
    if (tid < 192) qs[tid] = 0.f;
    if (tid < 96) { h[tid] = 0.f; c[tid] = 0.f; }
    __syncthreads();
    const int s = sse[0], t = sse[1];
    for (int step = 0; step < 3; ++step) {
        if (tid < 384) {
            float acc = b_ih[tid] + b_hh[tid];
            const float* wi = &w_ih[tid * 192];
#pragma unroll 8
            for (int k = 0; k < 192; ++k) acc = fmaf(qs[k], wi[k], acc);
            const float* wh = &w_hh[tid * 96];
#pragma unroll 8
            for (int k = 0; k < 96; ++k) acc = fmaf(h[k], wh[k], acc);
            gates[tid] = acc;
        }
        __syncthreads();
        if (tid < 96) {
            float ig = 1.f / (1.f + __expf(-gates[tid]));
            float fg = 1.f / (1.f + __expf(-gates[96 + tid]));
            float gg = tanhf(gates[192 + tid]);
            float og = 1.f / (1.f + __expf(-gates[288 + tid]));
            float cn = fg * c[tid] + ig * gg;
            c[tid] = cn;
            h[tid] = og * tanhf(cn);
        }
        __syncthreads();
        float pmax = -INFINITY;
        for (int n = s + tid; n < t; n += 512) {
            const float* xr = &xc[n * 96];
            float acc = 0.f;
#pragma unroll 8
            for (int k = 0; k < 96; ++k) acc = fmaf(xr[k], h[k], acc);
            e_ws[n] = acc;
            pmax = fmaxf(pmax, acc);
        }
#pragma unroll
        for (int off = 32; off > 0; off >>= 1) pmax = fmaxf(pmax, __shfl_down(pmax, off));
        if (lane == 0) redm[wid] = pmax;
        __syncthreads();
        if (tid == 0) {
            float m = redm[0];
#pragma unroll
            for (int i = 1; i < 8; ++i) m = fmaxf(m, redm[i]);
            if (!isfinite(m)) m = 0.f;
            sh_scal[0] = m;
        }
        __syncthreads();
        const float emax = sh_scal[0];
        float pa = 0.f;
        for (int n = s + tid; n < t; n += 512) {
            float a = __expf(e_ws[n] - emax);
            e_ws[n] = a;
            pa += a;
        }
#pragma unroll
        for (int off = 32; off > 0; off >>= 1) pa += __shfl_down(pa, off);
        if (lane == 0) reds[wid] = pa;
        __syncthreads();
        if (tid == 0) {
            float a2 = 0.f;
#pragma unroll
            for (int i = 0; i < 8; ++i) a2 += reds[i];
            sh_scal[1] = (a2 > 0.f) ? 1.f / a2 : 0.f;
        }
        __syncthreads();
        const int g = tid / 96, q = tid - g * 96;
        if (tid < 480) {
            float racc = 0.f;
            for (int n = s + g; n < t; n += 5)
                racc = fmaf(e_ws[n], xc[n * 96 + q], racc);
            racc_s[g][q] = racc;
        }
        __syncthreads();
        if (tid < 96) {
            float r = (racc_s[0][tid] + racc_s[1][tid] + racc_s[2][tid]
                     + racc_s[3][tid] + racc_s[4][tid]) * sh_scal[1];
            qs[tid] = h[tid];
            qs[96 + tid] = r;
        }
        __syncthreads();
    }
    if (tid < 192) qs_g[b * 192 + tid] = qs[tid];
}

// -------------------------------- xg = qs@s2s_w^T+b ; pre_m1 = relu(xg@m1^T+b)
__global__ __launch_bounds__(128) void k_xg(const float* __restrict__ qs_g,
        const float* __restrict__ sw, const float* __restrict__ sb,
        const float* __restrict__ m1w, const float* __restrict__ m1b,
        float* __restrict__ pre, float* __restrict__ gsum, float* __restrict__ gsumsq) {
    __shared__ float xg0[96];
    const int tid = threadIdx.x;
    const int b = blockIdx.x;
    if (tid < 96) {
        const float* q = &qs_g[b * 192];
        float acc = sb[tid];
        const float* w = &sw[tid * 192];
#pragma unroll 8
        for (int k = 0; k < 192; ++k) acc = fmaf(q[k], w[k], acc);
        xg0[tid] = acc;
    }
    __syncthreads();
    if (tid < 96) {
        float acc = m1b[tid];
        const float* w = &m1w[tid * 96];
#pragma unroll 8
        for (int k = 0; k < 96; ++k) acc = fmaf(xg0[k], w[k], acc);
        float r = fmaxf(acc, 0.f);
        pre[b * 96 + tid] = r;
        atomicAdd(&gsum[tid], r);
        atomicAdd(&gsumsq[tid], r * r);
    }
}

// ----------------------------------------- tail: BN(m1) -> m2 linear+relu+BN
__global__ __launch_bounds__(256) void k_tail(const float* __restrict__ pre,
        const float* __restrict__ gsum, const float* __restrict__ gsumsq,
        const float* __restrict__ g1, const float* __restrict__ beta1,
        const float* __restrict__ m2w, const float* __restrict__ m2b,
        const float* __restrict__ g2, const float* __restrict__ beta2,
        float* __restrict__ out) {
    __shared__ float xg1[100][97];
    __shared__ float pre2[200];
    __shared__ float ab2[4];
    const int tid = threadIdx.x;
    if (tid < 96) {
        const float invN = 1.f / NG;
        float mean = gsum[tid] * invN;
        float var = fmaxf(gsumsq[tid] * invN - mean * mean, 0.f);
        float a = g1[tid] * rsqrtf(var + EPS);
        float bb = beta1[tid] - mean * a;
        for (int n = 0; n < NG; ++n)
            xg1[n][tid] = fmaf(a, pre[n * 96 + tid], bb);
    }
    __syncthreads();
    if (tid < 200) {
        int n = tid >> 1, cc = tid & 1;
        float acc = m2b[cc];
        const float* w = &m2w[cc * 96];
#pragma unroll 8
        for (int k = 0; k < 96; ++k) acc = fmaf(xg1[n][k], w[k], acc);
        pre2[tid] = fmaxf(acc, 0.f);
    }
    __syncthreads();
    if (tid < 2) {
        float s = 0.f, ss = 0.f;
        for (int n = 0; n < NG; ++n) { float v = pre2[n * 2 + tid]; s += v; ss = fmaf(v, v, ss); }
        const float invN = 1.f / NG;
        float mean = s * invN;
        float var = fmaxf(ss * invN - mean * mean, 0.f);
        float a = g2[tid] * rsqrtf(var + EPS);
        ab2[tid] = a;
        ab2[2 + tid] = beta2[tid] - mean * a;
    }
    __syncthreads();
    if (tid < 200) {
        int cc = tid & 1;
        out[tid] = fmaf(ab2[cc], pre2[tid], ab2[2 + cc]);
    }
}

extern "C" void kernel_launch(void* const* d_in, const int* in_sizes, int n_in,
                              void* d_out, int out_size, void* d_ws, size_t ws_size,
                              hipStream_t stream) {
    (void)in_sizes; (void)n_in; (void)out_size; (void)ws_size;
    const float* x       = (const float*)d_in[0];
    const float* ea      = (const float*)d_in[1];
    const float* c1w     = (const float*)d_in[2];
    const float* c1b     = (const float*)d_in[3];
    const float* c1g     = (const float*)d_in[4];
    const float* c1beta  = (const float*)d_in[5];
    const float* c1root  = (const float*)d_in[6];
    const float* c1bias  = (const float*)d_in[7];
    const float* c2w     = (const float*)d_in[8];
    const float* c2b     = (const float*)d_in[9];
    const float* c2g     = (const float*)d_in[10];
    const float* c2beta  = (const float*)d_in[11];
    const float* c2root  = (const float*)d_in[12];
    const float* c2bias  = (const float*)d_in[13];
    const float* lin1w   = (const float*)d_in[14];
    const float* lin1b   = (const float*)d_in[15];
    const float* lin1g   = (const float*)d_in[16];
    const float* lin1bt  = (const float*)d_in[17];
    const float* wih     = (const float*)d_in[18];
    const float* whh     = (const float*)d_in[19];
    const float* bih     = (const float*)d_in[20];
    const float* bhh     = (const float*)d_in[21];
    const float* s2sw    = (const float*)d_in[22];
    const float* s2sb    = (const float*)d_in[23];
    const float* m1w     = (const float*)d_in[24];
    const float* m1b     = (const float*)d_in[25];
    const float* m1g     = (const float*)d_in[26];
    const float* m1beta  = (const float*)d_in[27];
    const float* m2w     = (const float*)d_in[28];
    const float* m2b     = (const float*)d_in[29];
    const float* m2g     = (const float*)d_in[30];
    const float* m2beta  = (const float*)d_in[31];
    const int* src       = (const int*)d_in[32];
    const int* dst       = (const int*)d_in[33];
    const int* batch     = (const int*)d_in[34];

    float* ws = (float*)d_ws;
    float* stats  = ws;                 // 4096
    float* AB     = ws + 4096;          // 4096: A1|B1|A2|B2
    float* linst  = ws + 8192;          // 192
    float* m1st   = ws + 8384;          // 192
    float* x1     = ws + 8704;          // 320000
    float* x2     = x1 + 320000;        // 320000
    float* prelin = x2 + 320000;        // 960000 (BN in-place -> xc)
    float* e_ws   = prelin + 960000;    // 10000
    float* qs_g   = e_ws + 10000;       // 19200
    float* prem1  = qs_g + 19200;       // 9600

    hipMemsetAsync(ws, 0, 8576 * sizeof(float), stream);

    // ---- fused BN stats for both convs (float2-paired cols, LDS-staged ea)
    k_stats4<<<1250, 512, 0, stream>>>(ea, c1w, c1b, c2w, c2b, stats);

    // ---- conv1 (root1 also computes both convs' BN affines in its last block)
    k_root<<<1251, 256, 0, stream>>>(x, c1root, c1bias, x1,
                                     1, stats, c1g, c1beta, c2g, c2beta, AB);
    k_conv<<<1024, 512, 0, stream>>>(x, ea, src, dst, c1w, c1b, AB, AB + 1024, x1);

    // ---- conv2
    k_root<<<1250, 256, 0, stream>>>(x1, c2root, c2bias, x2,
                                     0, stats, c1g, c1beta, c2g, c2beta, AB);
    k_conv<<<1024, 512, 0, stream>>>(x1, ea, src, dst, c2w, c2b, AB + 2048, AB + 3072, x2);

    // ---- lin1 (Linear+ReLU+BN)
    k_lin1a<<<500, 384, 0, stream>>>(x1, x2, lin1w, lin1b, prelin, linst, linst + 96);
    k_lin1b<<<500, 384, 0, stream>>>(linst, linst + 96, lin1g, lin1bt, prelin, prelin);

    // ---- Set2Set (graph ranges found in-kernel)
    k_s2s<<<100, 512, 0, stream>>>(prelin, batch, wih, whh, bih, bhh, qs_g, e_ws);

    // ---- tail MLPs
    k_xg<<<100, 128, 0, stream>>>(qs_g, s2sw, s2sb, m1w, m1b, prem1, m1st, m1st + 96);
    k_tail<<<1, 256, 0, stream>>>(prem1, m1st, m1st + 96, m1g, m1beta,
                                  m2w, m2b, m2g, m2beta, (float*)d_out);
}

// Round 11
// 385.819 us; speedup vs baseline: 1.3509x; 1.3509x over previous
//
#include <hip/hip_runtime.h>
#include <math.h>

#define NN 10000       // N_NODES
#define NE 160000      // N_EDGES
#define NG 100         // N_GRAPHS
#define DD 32
#define QQ 96
#define EPS 1e-5f

// ---------------- fused BN stats for BOTH convs' edge-MLPs (R9 version, kept).
__global__ __launch_bounds__(512) void k_stats4(const float* __restrict__ ea,
        const float* __restrict__ w1, const float* __restrict__ b1,
        const float* __restrict__ w2, const float* __restrict__ b2,
        float* __restrict__ stats) {
    __shared__ float eas[1536];   // 256 edges x 6 attrs
    const int tid = threadIdx.x;
    const int chunk = blockIdx.x >> 1;
    const int ct = ((blockIdx.x & 1) << 9) | tid;   // column 0..1023
    const float* wr1 = w1 + ct * 6;
    const float* wr2 = w2 + ct * 6;
    float2 W0 = make_float2(wr1[0], wr2[0]);
    float2 W1 = make_float2(wr1[1], wr2[1]);
    float2 W2 = make_float2(wr1[2], wr2[2]);
    float2 W3 = make_float2(wr1[3], wr2[3]);
    float2 W4 = make_float2(wr1[4], wr2[4]);
    float2 W5 = make_float2(wr1[5], wr2[5]);
    float2 Bb = make_float2(b1[ct], b2[ct]);
    float2 S = make_float2(0.f, 0.f), SS = make_float2(0.f, 0.f);
    const int base = chunk * 1536;
    eas[tid]        = ea[base + tid];
    eas[tid + 512]  = ea[base + tid + 512];
    eas[tid + 1024] = ea[base + tid + 1024];
    __syncthreads();
#pragma unroll 4
    for (int el = 0; el < 256; ++el) {
        const float* ep = &eas[el * 6];           // wave-uniform -> broadcast
        float2 p0 = *reinterpret_cast<const float2*>(ep);
        float2 p1 = *reinterpret_cast<const float2*>(ep + 2);
        float2 p2 = *reinterpret_cast<const float2*>(ep + 4);
        float2 y = Bb;
        y.x = fmaf(p0.x, W0.x, y.x); y.y = fmaf(p0.x, W0.y, y.y);
        y.x = fmaf(p0.y, W1.x, y.x); y.y = fmaf(p0.y, W1.y, y.y);
        y.x = fmaf(p1.x, W2.x, y.x); y.y = fmaf(p1.x, W2.y, y.y);
        y.x = fmaf(p1.y, W3.x, y.x); y.y = fmaf(p1.y, W3.y, y.y);
        y.x = fmaf(p2.x, W4.x, y.x); y.y = fmaf(p2.x, W4.y, y.y);
        y.x = fmaf(p2.y, W5.x, y.x); y.y = fmaf(p2.y, W5.y, y.y);
        float rx = fmaxf(y.x, 0.f), ry = fmaxf(y.y, 0.f);
        S.x += rx; S.y += ry;
        SS.x = fmaf(rx, rx, SS.x); SS.y = fmaf(ry, ry, SS.y);
    }
    atomicAdd(&stats[ct], S.x);
    atomicAdd(&stats[1024 + ct], SS.x);
    atomicAdd(&stats[2048 + ct], S.y);
    atomicAdd(&stats[3072 + ct], SS.y);
}

// -------- k_root: out[n,o] = bias[o] + x[n]@root.  Block gridDim-1 (optional,
// when doFin!=0) instead computes BOTH convs' BN affines from stats.
__global__ __launch_bounds__(256) void k_root(const float* __restrict__ x,
        const float* __restrict__ root, const float* __restrict__ bias,
        float* __restrict__ out,
        int doFin, const float* __restrict__ stats,
        const float* __restrict__ g1, const float* __restrict__ beta1,
        const float* __restrict__ g2, const float* __restrict__ beta2,
        float* __restrict__ AB) {
    const int tid = threadIdx.x;
    if (doFin && blockIdx.x == gridDim.x - 1) {
        const float invE = 1.f / NE;
        for (int j = tid; j < 2048; j += 256) {
            int cv = j >> 10, col = j & 1023;
            const float* st = stats + cv * 2048;
            const float* g = cv ? g2 : g1;
            const float* bt = cv ? beta2 : beta1;
            float mean = st[col] * invE;
            float var = fmaxf(st[1024 + col] * invE - mean * mean, 0.f);
            float a = g[col] * rsqrtf(var + EPS);
            AB[cv * 2048 + col] = a;
            AB[cv * 2048 + 1024 + col] = bt[col] - mean * a;
        }
        return;
    }
    __shared__ float rlds[1024];
#pragma unroll
    for (int r = 0; r < 4; ++r) rlds[tid + 256 * r] = root[tid + 256 * r];
    __syncthreads();
    const int o = tid & 31;
    const int gg = tid >> 5;
    const int n = blockIdx.x * 8 + gg;
    if (n >= NN) return;
    const int half = tid & 32;
    float xs = x[n * 32 + o];
    float acc = bias[o];
#pragma unroll
    for (int i = 0; i < 32; ++i) {
        float xi = __shfl(xs, half | i);
        acc = fmaf(xi, rlds[i * 32 + o], acc);
    }
    out[n * 32 + o] = acc;
}

// ------------- NNConv v4: 256-thr/4-wave blocks, contiguous 160-edge range per
// block, 8-edge chunks. Phase A: wave w computes i in [8w,8w+8) partials
// (4 cols/lane) -> LDS. Phase B: cross-wave sum in LDS, ONE 32-lane atomic
// flush per edge (32 atomics/edge vs 128 in R9 -> 4x less write-through;
// R9/R10 showed fp32 atomics write through to HBM at ~940 GB/s and dominate).
#define CDECL(K) float w##K##0, w##K##1, w##K##2, w##K##3, w##K##4, w##K##5, bs##K, av##K, bv##K;
#define CLOAD(K) { const int _j = (((w << 3) + (K << 1) + p) << 5) | o; \
    const float* _wr = nw + _j * 6; \
    w##K##0 = _wr[0]; w##K##1 = _wr[1]; w##K##2 = _wr[2]; \
    w##K##3 = _wr[3]; w##K##4 = _wr[4]; w##K##5 = _wr[5]; \
    bs##K = nb[_j]; av##K = A[_j]; bv##K = B[_j]; }
#define CPIN(K) asm("" : "+v"(w##K##0), "+v"(w##K##1), "+v"(w##K##2), "+v"(w##K##3), \
                         "+v"(w##K##4), "+v"(w##K##5), "+v"(bs##K), "+v"(av##K), "+v"(bv##K));
#define CACC(K, XK, M) { float _y = bs##K; \
    _y = fmaf(e0, w##K##0, _y); _y = fmaf(e1, w##K##1, _y); _y = fmaf(e2, w##K##2, _y); \
    _y = fmaf(e3, w##K##3, _y); _y = fmaf(e4, w##K##4, _y); _y = fmaf(e5, w##K##5, _y); \
    float _t = fmaf(av##K, fmaxf(_y, 0.f), bv##K); M = fmaf(XK, _t, M); }

__global__ __launch_bounds__(256) void k_conv(const float* __restrict__ xin,
        const float* __restrict__ ea, const int* __restrict__ src, const int* __restrict__ dst,
        const float* __restrict__ nw, const float* __restrict__ nb,
        const float* __restrict__ A, const float* __restrict__ B,
        float* __restrict__ agg) {
    __shared__ float part[4][8][32];
    const int tid = threadIdx.x;
    const int lane = tid & 63;
    const int w = tid >> 6;        // wave = i-quarter (i = 8w .. 8w+7)
    const int p = lane >> 5;
    const int o = lane & 31;

    CDECL(0) CDECL(1) CDECL(2) CDECL(3)
    CLOAD(0) CLOAD(1) CLOAD(2) CLOAD(3)
    CPIN(0) CPIN(1) CPIN(2) CPIN(3)

    const int base0 = blockIdx.x * 160;   // 1000 blocks * 160 edges = NE
    for (int ch = 0; ch < 20; ++ch) {
        const int base = base0 + ch * 8;
        // ---- phase A: per-wave i-quarter partials for 8 edges
#pragma unroll 2
        for (int m = 0; m < 8; ++m) {
            const int e = base + m;
            const int sc = src[e];                 // block-uniform -> s_load
            const float* er = ea + e * 6;
            float e0 = er[0], e1 = er[1], e2 = er[2], e3 = er[3], e4 = er[4], e5 = er[5];
            const float* xr = xin + sc * 32 + (w << 3);
            float4 qa = *reinterpret_cast<const float4*>(xr);
            float4 qb = *reinterpret_cast<const float4*>(xr + 4);
            float xA = p ? qa.y : qa.x, xB = p ? qa.w : qa.z;
            float xC = p ? qb.y : qb.x, xD = p ? qb.w : qb.z;
            float msg = 0.f;
            CACC(0, xA, msg) CACC(1, xB, msg) CACC(2, xC, msg) CACC(3, xD, msg)
            msg += __shfl_xor(msg, 32, 64);
            if (p == 0) part[w][m][o] = msg;
        }
        __syncthreads();
        // ---- phase B: cross-wave sum + single 32-lane atomic flush per edge
        {
            const int m = (w << 1) | p;            // wave w handles edges 2w, 2w+1
            const int e = base + m;
            const int dd = dst[e];
            float sum = part[0][m][o] + part[1][m][o] + part[2][m][o] + part[3][m][o];
            atomicAdd(&agg[dd * 32 + o], sum);
        }
        __syncthreads();
    }
}

// ---------------------------------------- lin1: relu(cat(x1,x2)@W^T+b) + stats
__global__ __launch_bounds__(384) void k_lin1a(const float* __restrict__ x1,
        const float* __restrict__ x2, const float* __restrict__ lw, const float* __restrict__ lb,
        float* __restrict__ pre, float* __restrict__ gsum, float* __restrict__ gsumsq) {
    __shared__ float cat[4][64];
    __shared__ float sh_s[96], sh_ss[96];
    const int tid = threadIdx.x;
    const int np = tid / 96;   // 0..3
    const int q = tid - np * 96;
    float w[64];
#pragma unroll
    for (int k = 0; k < 64; ++k) w[k] = lw[q * 64 + k];
    const float bq = lb[q];
    float s = 0.f, ss = 0.f;
    for (int nb = blockIdx.x * 4; nb < NN; nb += gridDim.x * 4) {
        __syncthreads();
        if (tid < 256) {
            int n2 = tid >> 6, k = tid & 63;
            cat[n2][k] = (k < 32) ? x1[(nb + n2) * 32 + k] : x2[(nb + n2) * 32 + (k - 32)];
        }
        __syncthreads();
        float v = bq;
#pragma unroll
        for (int k = 0; k < 64; ++k) v = fmaf(cat[np][k], w[k], v);
        float r = fmaxf(v, 0.f);
        pre[(nb + np) * 96 + q] = r;
        s += r; ss = fmaf(r, r, ss);
    }
    __syncthreads();
    if (tid < 96) { sh_s[tid] = 0.f; sh_ss[tid] = 0.f; }
    __syncthreads();
    atomicAdd(&sh_s[q], s);
    atomicAdd(&sh_ss[q], ss);
    __syncthreads();
    if (tid < 96) {
        atomicAdd(&gsum[tid], sh_s[tid]);
        atomicAdd(&gsumsq[tid], sh_ss[tid]);
    }
}

__global__ __launch_bounds__(384) void k_lin1b(const float* __restrict__ gsum,
        const float* __restrict__ gsumsq, const float* __restrict__ g, const float* __restrict__ beta,
        const float* __restrict__ pre, float* __restrict__ xc) {
    const int tid = threadIdx.x;
    const int np = tid / 96;
    const int q = tid - np * 96;
    const float invN = 1.f / NN;
    float mean = gsum[q] * invN;
    float var = fmaxf(gsumsq[q] * invN - mean * mean, 0.f);
    float a = g[q] * rsqrtf(var + EPS);
    float b = beta[q] - mean * a;
    for (int nb = blockIdx.x * 4; nb < NN; nb += gridDim.x * 4) {
        int n = nb + np;
        xc[n * 96 + q] = fmaf(a, pre[n * 96 + q], b);
    }
}

// ------------------------------------------------- Set2Set: whole loop per graph
__global__ __launch_bounds__(512) void k_s2s(const float* __restrict__ xc,
        const int* __restrict__ batch,
        const float* __restrict__ w_ih, const float* __restrict__ w_hh,
        const float* __restrict__ b_ih, const float* __restrict__ b_hh,
        float* __restrict__ qs_g, float* __restrict__ e_ws) {
    __shared__ float qs[192], h[96], c[96], gates[384];
    __shared__ float redm[8], reds[8];
    __shared__ float racc_s[5][96];
    __shared__ float sh_scal[2];   // [0]=emax, [1]=1/asum
    __shared__ int sse[2];
    const int tid = threadIdx.x;
    const int wid = tid >> 6, lane = tid & 63;
    const int b = blockIdx.x;
    if (tid < 2) {   // inline graph-range binary search (start of graph b+tid)
        int key = b + tid, lo = 0, hi = NN;
        while (lo < hi) { int mid = (lo + hi) >> 1; if (batch[mid] < key) lo = mid + 1; else hi = mid; }
        sse[tid] = lo;
    }
    if (tid < 192) qs[tid] = 0.f;
    if (tid < 96) { h[tid] = 0.f; c[tid] = 0.f; }
    __syncthreads();
    const int s = sse[0], t = sse[1];
    for (int step = 0; step < 3; ++step) {
        if (tid < 384) {
            float acc = b_ih[tid] + b_hh[tid];
            const float* wi = &w_ih[tid * 192];
#pragma unroll 8
            for (int k = 0; k < 192; ++k) acc = fmaf(qs[k], wi[k], acc);
            const float* wh = &w_hh[tid * 96];
#pragma unroll 8
            for (int k = 0; k < 96; ++k) acc = fmaf(h[k], wh[k], acc);
            gates[tid] = acc;
        }
        __syncthreads();
        if (tid < 96) {
            float ig = 1.f / (1.f + __expf(-gates[tid]));
            float fg = 1.f / (1.f + __expf(-gates[96 + tid]));
            float gg = tanhf(gates[192 + tid]);
            float og = 1.f / (1.f + __expf(-gates[288 + tid]));
            float cn = fg * c[tid] + ig * gg;
            c[tid] = cn;
            h[tid] = og * tanhf(cn);
        }
        __syncthreads();
        float pmax = -INFINITY;
        for (int n = s + tid; n < t; n += 512) {
            const float* xr = &xc[n * 96];
            float acc = 0.f;
#pragma unroll 8
            for (int k = 0; k < 96; ++k) acc = fmaf(xr[k], h[k], acc);
            e_ws[n] = acc;
            pmax = fmaxf(pmax, acc);
        }
#pragma unroll
        for (int off = 32; off > 0; off >>= 1) pmax = fmaxf(pmax, __shfl_down(pmax, off));
        if (lane == 0) redm[wid] = pmax;
        __syncthreads();
        if (tid == 0) {
            float m = redm[0];
#pragma unroll
            for (int i = 1; i < 8; ++i) m = fmaxf(m, redm[i]);
            if (!isfinite(m)) m = 0.f;
            sh_scal[0] = m;
        }
        __syncthreads();
        const float emax = sh_scal[0];
        float pa = 0.f;
        for (int n = s + tid; n < t; n += 512) {
            float a = __expf(e_ws[n] - emax);
            e_ws[n] = a;
            pa += a;
        }
#pragma unroll
        for (int off = 32; off > 0; off >>= 1) pa += __shfl_down(pa, off);
        if (lane == 0) reds[wid] = pa;
        __syncthreads();
        if (tid == 0) {
            float a2 = 0.f;
#pragma unroll
            for (int i = 0; i < 8; ++i) a2 += reds[i];
            sh_scal[1] = (a2 > 0.f) ? 1.f / a2 : 0.f;
        }
        __syncthreads();
        const int g = tid / 96, q = tid - g * 96;
        if (tid < 480) {
            float racc = 0.f;
            for (int n = s + g; n < t; n += 5)
                racc = fmaf(e_ws[n], xc[n * 96 + q], racc);
            racc_s[g][q] = racc;
        }
        __syncthreads();
        if (tid < 96) {
            float r = (racc_s[0][tid] + racc_s[1][tid] + racc_s[2][tid]
                     + racc_s[3][tid] + racc_s[4][tid]) * sh_scal[1];
            qs[tid] = h[tid];
            qs[96 + tid] = r;
        }
        __syncthreads();
    }
    if (tid < 192) qs_g[b * 192 + tid] = qs[tid];
}

// -------------------------------- xg = qs@s2s_w^T+b ; pre_m1 = relu(xg@m1^T+b)
__global__ __launch_bounds__(128) void k_xg(const float* __restrict__ qs_g,
        const float* __restrict__ sw, const float* __restrict__ sb,
        const float* __restrict__ m1w, const float* __restrict__ m1b,
        float* __restrict__ pre, float* __restrict__ gsum, float* __restrict__ gsumsq) {
    __shared__ float xg0[96];
    const int tid = threadIdx.x;
    const int b = blockIdx.x;
    if (tid < 96) {
        const float* q = &qs_g[b * 192];
        float acc = sb[tid];
        const float* w = &sw[tid * 192];
#pragma unroll 8
        for (int k = 0; k < 192; ++k) acc = fmaf(q[k], w[k], acc);
        xg0[tid] = acc;
    }
    __syncthreads();
    if (tid < 96) {
        float acc = m1b[tid];
        const float* w = &m1w[tid * 96];
#pragma unroll 8
        for (int k = 0; k < 96; ++k) acc = fmaf(xg0[k], w[k], acc);
        float r = fmaxf(acc, 0.f);
        pre[b * 96 + tid] = r;
        atomicAdd(&gsum[tid], r);
        atomicAdd(&gsumsq[tid], r * r);
    }
}

// ----------------------------------------- tail: BN(m1) -> m2 linear+relu+BN
__global__ __launch_bounds__(256) void k_tail(const float* __restrict__ pre,
        const float* __restrict__ gsum, const float* __restrict__ gsumsq,
        const float* __restrict__ g1, const float* __restrict__ beta1,
        const float* __restrict__ m2w, const float* __restrict__ m2b,
        const float* __restrict__ g2, const float* __restrict__ beta2,
        float* __restrict__ out) {
    __shared__ float xg1[100][97];
    __shared__ float pre2[200];
    __shared__ float ab2[4];
    const int tid = threadIdx.x;
    if (tid < 96) {
        const float invN = 1.f / NG;
        float mean = gsum[tid] * invN;
        float var = fmaxf(gsumsq[tid] * invN - mean * mean, 0.f);
        float a = g1[tid] * rsqrtf(var + EPS);
        float bb = beta1[tid] - mean * a;
        for (int n = 0; n < NG; ++n)
            xg1[n][tid] = fmaf(a, pre[n * 96 + tid], bb);
    }
    __syncthreads();
    if (tid < 200) {
        int n = tid >> 1, cc = tid & 1;
        float acc = m2b[cc];
        const float* w = &m2w[cc * 96];
#pragma unroll 8
        for (int k = 0; k < 96; ++k) acc = fmaf(xg1[n][k], w[k], acc);
        pre2[tid] = fmaxf(acc, 0.f);
    }
    __syncthreads();
    if (tid < 2) {
        float s = 0.f, ss = 0.f;
        for (int n = 0; n < NG; ++n) { float v = pre2[n * 2 + tid]; s += v; ss = fmaf(v, v, ss); }
        const float invN = 1.f / NG;
        float mean = s * invN;
        float var = fmaxf(ss * invN - mean * mean, 0.f);
        float a = g2[tid] * rsqrtf(var + EPS);
        ab2[tid] = a;
        ab2[2 + tid] = beta2[tid] - mean * a;
    }
    __syncthreads();
    if (tid < 200) {
        int cc = tid & 1;
        out[tid] = fmaf(ab2[cc], pre2[tid], ab2[2 + cc]);
    }
}

extern "C" void kernel_launch(void* const* d_in, const int* in_sizes, int n_in,
                              void* d_out, int out_size, void* d_ws, size_t ws_size,
                              hipStream_t stream) {
    (void)in_sizes; (void)n_in; (void)out_size; (void)ws_size;
    const float* x       = (const float*)d_in[0];
    const float* ea      = (const float*)d_in[1];
    const float* c1w     = (const float*)d_in[2];
    const float* c1b     = (const float*)d_in[3];
    const float* c1g     = (const float*)d_in[4];
    const float* c1beta  = (const float*)d_in[5];
    const float* c1root  = (const float*)d_in[6];
    const float* c1bias  = (const float*)d_in[7];
    const float* c2w     = (const float*)d_in[8];
    const float* c2b     = (const float*)d_in[9];
    const float* c2g     = (const float*)d_in[10];
    const float* c2beta  = (const float*)d_in[11];
    const float* c2root  = (const float*)d_in[12];
    const float* c2bias  = (const float*)d_in[13];
    const float* lin1w   = (const float*)d_in[14];
    const float* lin1b   = (const float*)d_in[15];
    const float* lin1g   = (const float*)d_in[16];
    const float* lin1bt  = (const float*)d_in[17];
    const float* wih     = (const float*)d_in[18];
    const float* whh     = (const float*)d_in[19];
    const float* bih     = (const float*)d_in[20];
    const float* bhh     = (const float*)d_in[21];
    const float* s2sw    = (const float*)d_in[22];
    const float* s2sb    = (const float*)d_in[23];
    const float* m1w     = (const float*)d_in[24];
    const float* m1b     = (const float*)d_in[25];
    const float* m1g     = (const float*)d_in[26];
    const float* m1beta  = (const float*)d_in[27];
    const float* m2w     = (const float*)d_in[28];
    const float* m2b     = (const float*)d_in[29];
    const float* m2g     = (const float*)d_in[30];
    const float* m2beta  = (const float*)d_in[31];
    const int* src       = (const int*)d_in[32];
    const int* dst       = (const int*)d_in[33];
    const int* batch     = (const int*)d_in[34];

    float* ws = (float*)d_ws;
    float* stats  = ws;                 // 4096
    float* AB     = ws + 4096;          // 4096: A1|B1|A2|B2
    float* linst  = ws + 8192;          // 192
    float* m1st   = ws + 8384;          // 192
    float* x1     = ws + 8704;          // 320000
    float* x2     = x1 + 320000;        // 320000
    float* prelin = x2 + 320000;        // 960000 (BN in-place -> xc)
    float* e_ws   = prelin + 960000;    // 10000
    float* qs_g   = e_ws + 10000;       // 19200
    float* prem1  = qs_g + 19200;       // 9600

    hipMemsetAsync(ws, 0, 8576 * sizeof(float), stream);

    // ---- fused BN stats for both convs (float2-paired cols, LDS-staged ea)
    k_stats4<<<1250, 512, 0, stream>>>(ea, c1w, c1b, c2w, c2b, stats);

    // ---- conv1 (root1 also computes both convs' BN affines in its last block)
    k_root<<<1251, 256, 0, stream>>>(x, c1root, c1bias, x1,
                                     1, stats, c1g, c1beta, c2g, c2beta, AB);
    k_conv<<<1000, 256, 0, stream>>>(x, ea, src, dst, c1w, c1b, AB, AB + 1024, x1);

    // ---- conv2
    k_root<<<1250, 256, 0, stream>>>(x1, c2root, c2bias, x2,
                                     0, stats, c1g, c1beta, c2g, c2beta, AB);
    k_conv<<<1000, 256, 0, stream>>>(x1, ea, src, dst, c2w, c2b, AB + 2048, AB + 3072, x2);

    // ---- lin1 (Linear+ReLU+BN)
    k_lin1a<<<500, 384, 0, stream>>>(x1, x2, lin1w, lin1b, prelin, linst, linst + 96);
    k_lin1b<<<500, 384, 0, stream>>>(linst, linst + 96, lin1g, lin1bt, prelin, prelin);

    // ---- Set2Set (graph ranges found in-kernel)
    k_s2s<<<100, 512, 0, stream>>>(prelin, batch, wih, whh, bih, bhh, qs_g, e_ws);

    // ---- tail MLPs
    k_xg<<<100, 128, 0, stream>>>(qs_g, s2sw, s2sb, m1w, m1b, prem1, m1st, m1st + 96);
    k_tail<<<1, 256, 0, stream>>>(prem1, m1st, m1st + 96, m1g, m1beta,
                                  m2w, m2b, m2g, m2beta, (float*)d_out);
}

// Round 12
// 318.902 us; speedup vs baseline: 1.6344x; 1.2098x over previous
//
#include <hip/hip_runtime.h>
#include <math.h>

#define NN 10000       // N_NODES
#define NE 160000      // N_EDGES
#define NG 100         // N_GRAPHS
#define DD 32
#define QQ 96
#define EPS 1e-5f

// ---------------- fused BN stats for BOTH convs' edge-MLPs (R9 version, kept).
__global__ __launch_bounds__(512) void k_stats4(const float* __restrict__ ea,
        const float* __restrict__ w1, const float* __restrict__ b1,
        const float* __restrict__ w2, const float* __restrict__ b2,
        float* __restrict__ stats) {
    __shared__ float eas[1536];   // 256 edges x 6 attrs
    const int tid = threadIdx.x;
    const int chunk = blockIdx.x >> 1;
    const int ct = ((blockIdx.x & 1) << 9) | tid;   // column 0..1023
    const float* wr1 = w1 + ct * 6;
    const float* wr2 = w2 + ct * 6;
    float2 W0 = make_float2(wr1[0], wr2[0]);
    float2 W1 = make_float2(wr1[1], wr2[1]);
    float2 W2 = make_float2(wr1[2], wr2[2]);
    float2 W3 = make_float2(wr1[3], wr2[3]);
    float2 W4 = make_float2(wr1[4], wr2[4]);
    float2 W5 = make_float2(wr1[5], wr2[5]);
    float2 Bb = make_float2(b1[ct], b2[ct]);
    float2 S = make_float2(0.f, 0.f), SS = make_float2(0.f, 0.f);
    const int base = chunk * 1536;
    eas[tid]        = ea[base + tid];
    eas[tid + 512]  = ea[base + tid + 512];
    eas[tid + 1024] = ea[base + tid + 1024];
    __syncthreads();
#pragma unroll 4
    for (int el = 0; el < 256; ++el) {
        const float* ep = &eas[el * 6];           // wave-uniform -> broadcast
        float2 p0 = *reinterpret_cast<const float2*>(ep);
        float2 p1 = *reinterpret_cast<const float2*>(ep + 2);
        float2 p2 = *reinterpret_cast<const float2*>(ep + 4);
        float2 y = Bb;
        y.x = fmaf(p0.x, W0.x, y.x); y.y = fmaf(p0.x, W0.y, y.y);
        y.x = fmaf(p0.y, W1.x, y.x); y.y = fmaf(p0.y, W1.y, y.y);
        y.x = fmaf(p1.x, W2.x, y.x); y.y = fmaf(p1.x, W2.y, y.y);
        y.x = fmaf(p1.y, W3.x, y.x); y.y = fmaf(p1.y, W3.y, y.y);
        y.x = fmaf(p2.x, W4.x, y.x); y.y = fmaf(p2.x, W4.y, y.y);
        y.x = fmaf(p2.y, W5.x, y.x); y.y = fmaf(p2.y, W5.y, y.y);
        float rx = fmaxf(y.x, 0.f), ry = fmaxf(y.y, 0.f);
        S.x += rx; S.y += ry;
        SS.x = fmaf(rx, rx, SS.x); SS.y = fmaf(ry, ry, SS.y);
    }
    atomicAdd(&stats[ct], S.x);
    atomicAdd(&stats[1024 + ct], SS.x);
    atomicAdd(&stats[2048 + ct], S.y);
    atomicAdd(&stats[3072 + ct], SS.y);
}

// -------- k_root: out[n,o] = bias[o] + x[n]@root.  Block gridDim-1 (optional,
// when doFin!=0) instead computes BOTH convs' BN affines from stats.
__global__ __launch_bounds__(256) void k_root(const float* __restrict__ x,
        const float* __restrict__ root, const float* __restrict__ bias,
        float* __restrict__ out,
        int doFin, const float* __restrict__ stats,
        const float* __restrict__ g1, const float* __restrict__ beta1,
        const float* __restrict__ g2, const float* __restrict__ beta2,
        float* __restrict__ AB) {
    const int tid = threadIdx.x;
    if (doFin && blockIdx.x == gridDim.x - 1) {
        const float invE = 1.f / NE;
        for (int j = tid; j < 2048; j += 256) {
            int cv = j >> 10, col = j & 1023;
            const float* st = stats + cv * 2048;
            const float* g = cv ? g2 : g1;
            const float* bt = cv ? beta2 : beta1;
            float mean = st[col] * invE;
            float var = fmaxf(st[1024 + col] * invE - mean * mean, 0.f);
            float a = g[col] * rsqrtf(var + EPS);
            AB[cv * 2048 + col] = a;
            AB[cv * 2048 + 1024 + col] = bt[col] - mean * a;
        }
        return;
    }
    __shared__ float rlds[1024];
#pragma unroll
    for (int r = 0; r < 4; ++r) rlds[tid + 256 * r] = root[tid + 256 * r];
    __syncthreads();
    const int o = tid & 31;
    const int gg = tid >> 5;
    const int n = blockIdx.x * 8 + gg;
    if (n >= NN) return;
    const int half = tid & 32;
    float xs = x[n * 32 + o];
    float acc = bias[o];
#pragma unroll
    for (int i = 0; i < 32; ++i) {
        float xi = __shfl(xs, half | i);
        acc = fmaf(xi, rlds[i * 32 + o], acc);
    }
    out[n * 32 + o] = acc;
}

// ------------- NNConv v5: 2000 blocks x 80 edges, chunks of 16 (10 barriers vs
// R11's 40), phase-A unroll 4 (deep gather pipeline), full occupancy (~31
// waves/CU vs R11's 15.6). Same 5.1M atomics (R11 proved WRITE=20MB ~ 21us,
// no longer the wall; R11's wall was occupancy+barrier frequency).
#define CDECL(K) float w##K##0, w##K##1, w##K##2, w##K##3, w##K##4, w##K##5, bs##K, av##K, bv##K;
#define CLOAD(K) { const int _j = (((w << 3) + (K << 1) + p) << 5) | o; \
    const float* _wr = nw + _j * 6; \
    w##K##0 = _wr[0]; w##K##1 = _wr[1]; w##K##2 = _wr[2]; \
    w##K##3 = _wr[3]; w##K##4 = _wr[4]; w##K##5 = _wr[5]; \
    bs##K = nb[_j]; av##K = A[_j]; bv##K = B[_j]; }
#define CPIN(K) asm("" : "+v"(w##K##0), "+v"(w##K##1), "+v"(w##K##2), "+v"(w##K##3), \
                         "+v"(w##K##4), "+v"(w##K##5), "+v"(bs##K), "+v"(av##K), "+v"(bv##K));
#define CACC(K, XK, M) { float _y = bs##K; \
    _y = fmaf(e0, w##K##0, _y); _y = fmaf(e1, w##K##1, _y); _y = fmaf(e2, w##K##2, _y); \
    _y = fmaf(e3, w##K##3, _y); _y = fmaf(e4, w##K##4, _y); _y = fmaf(e5, w##K##5, _y); \
    float _t = fmaf(av##K, fmaxf(_y, 0.f), bv##K); M = fmaf(XK, _t, M); }

__global__ __launch_bounds__(256) void k_conv(const float* __restrict__ xin,
        const float* __restrict__ ea, const int* __restrict__ src, const int* __restrict__ dst,
        const float* __restrict__ nw, const float* __restrict__ nb,
        const float* __restrict__ A, const float* __restrict__ B,
        float* __restrict__ agg) {
    __shared__ float part[4][16][32];   // 8 KB
    const int tid = threadIdx.x;
    const int lane = tid & 63;
    const int w = tid >> 6;        // wave = i-quarter (i = 8w .. 8w+7)
    const int p = lane >> 5;
    const int o = lane & 31;

    CDECL(0) CDECL(1) CDECL(2) CDECL(3)
    CLOAD(0) CLOAD(1) CLOAD(2) CLOAD(3)
    CPIN(0) CPIN(1) CPIN(2) CPIN(3)

    const int base0 = blockIdx.x * 80;   // 2000 blocks * 80 edges = NE
#pragma unroll 1
    for (int ch = 0; ch < 5; ++ch) {
        const int base = base0 + ch * 16;
        // ---- phase A: per-wave i-quarter partials for 16 edges (pipelined)
#pragma unroll 4
        for (int m = 0; m < 16; ++m) {
            const int e = base + m;
            const int sc = src[e];                 // block-uniform -> s_load
            const float* er = ea + e * 6;
            float e0 = er[0], e1 = er[1], e2 = er[2], e3 = er[3], e4 = er[4], e5 = er[5];
            const float* xr = xin + sc * 32 + (w << 3);
            float4 qa = *reinterpret_cast<const float4*>(xr);
            float4 qb = *reinterpret_cast<const float4*>(xr + 4);
            float xA = p ? qa.y : qa.x, xB = p ? qa.w : qa.z;
            float xC = p ? qb.y : qb.x, xD = p ? qb.w : qb.z;
            float msg = 0.f;
            CACC(0, xA, msg) CACC(1, xB, msg) CACC(2, xC, msg) CACC(3, xD, msg)
            msg += __shfl_xor(msg, 32, 64);
            if (p == 0) part[w][m][o] = msg;
        }
        __syncthreads();
        // ---- phase B: cross-wave sum + one 32-lane atomic per edge (2 edges/thread)
        {
            const int m = tid >> 5;                // 0..7
            const int e = base + m;
            const int dd = dst[e];
            float sum = part[0][m][o] + part[1][m][o] + part[2][m][o] + part[3][m][o];
            atomicAdd(&agg[dd * 32 + o], sum);
            const int m2 = m + 8;
            const int e2 = base + m2;
            const int dd2 = dst[e2];
            float sum2 = part[0][m2][o] + part[1][m2][o] + part[2][m2][o] + part[3][m2][o];
            atomicAdd(&agg[dd2 * 32 + o], sum2);
        }
        __syncthreads();
    }
}

// ---------------------------------------- lin1: relu(cat(x1,x2)@W^T+b) + stats
__global__ __launch_bounds__(384) void k_lin1a(const float* __restrict__ x1,
        const float* __restrict__ x2, const float* __restrict__ lw, const float* __restrict__ lb,
        float* __restrict__ pre, float* __restrict__ gsum, float* __restrict__ gsumsq) {
    __shared__ float cat[4][64];
    __shared__ float sh_s[96], sh_ss[96];
    const int tid = threadIdx.x;
    const int np = tid / 96;   // 0..3
    const int q = tid - np * 96;
    float w[64];
#pragma unroll
    for (int k = 0; k < 64; ++k) w[k] = lw[q * 64 + k];
    const float bq = lb[q];
    float s = 0.f, ss = 0.f;
    for (int nb = blockIdx.x * 4; nb < NN; nb += gridDim.x * 4) {
        __syncthreads();
        if (tid < 256) {
            int n2 = tid >> 6, k = tid & 63;
            cat[n2][k] = (k < 32) ? x1[(nb + n2) * 32 + k] : x2[(nb + n2) * 32 + (k - 32)];
        }
        __syncthreads();
        float v = bq;
#pragma unroll
        for (int k = 0; k < 64; ++k) v = fmaf(cat[np][k], w[k], v);
        float r = fmaxf(v, 0.f);
        pre[(nb + np) * 96 + q] = r;
        s += r; ss = fmaf(r, r, ss);
    }
    __syncthreads();
    if (tid < 96) { sh_s[tid] = 0.f; sh_ss[tid] = 0.f; }
    __syncthreads();
    atomicAdd(&sh_s[q], s);
    atomicAdd(&sh_ss[q], ss);
    __syncthreads();
    if (tid < 96) {
        atomicAdd(&gsum[tid], sh_s[tid]);
        atomicAdd(&gsumsq[tid], sh_ss[tid]);
    }
}

__global__ __launch_bounds__(384) void k_lin1b(const float* __restrict__ gsum,
        const float* __restrict__ gsumsq, const float* __restrict__ g, const float* __restrict__ beta,
        const float* __restrict__ pre, float* __restrict__ xc) {
    const int tid = threadIdx.x;
    const int np = tid / 96;
    const int q = tid - np * 96;
    const float invN = 1.f / NN;
    float mean = gsum[q] * invN;
    float var = fmaxf(gsumsq[q] * invN - mean * mean, 0.f);
    float a = g[q] * rsqrtf(var + EPS);
    float b = beta[q] - mean * a;
    for (int nb = blockIdx.x * 4; nb < NN; nb += gridDim.x * 4) {
        int n = nb + np;
        xc[n * 96 + q] = fmaf(a, pre[n * 96 + q], b);
    }
}

// ------------------------------------------------- Set2Set: whole loop per graph
__global__ __launch_bounds__(512) void k_s2s(const float* __restrict__ xc,
        const int* __restrict__ batch,
        const float* __restrict__ w_ih, const float* __restrict__ w_hh,
        const float* __restrict__ b_ih, const float* __restrict__ b_hh,
        float* __restrict__ qs_g, float* __restrict__ e_ws) {
    __shared__ float qs[192], h[96], c[96], gates[384];
    __shared__ float redm[8], reds[8];
    __shared__ float racc_s[5][96];
    __shared__ float sh_scal[2];   // [0]=emax, [1]=1/asum
    __shared__ int sse[2];
    const int tid = threadIdx.x;
    const int wid = tid >> 6, lane = tid & 63;
    const int b = blockIdx.x;
    if (tid < 2) {   // inline graph-range binary search (start of graph b+tid)
        int key = b + tid, lo = 0, hi = NN;
        while (lo < hi) { int mid = (lo + hi) >> 1; if (batch[mid] < key) lo = mid + 1; else hi = mid; }
        sse[tid] = lo;
    }
    if (tid < 192) qs[tid] = 0.f;
    if (tid < 96) { h[tid] = 0.f; c[tid] = 0.f; }
    __syncthreads();
    const int s = sse[0], t = sse[1];
    for (int step = 0; step < 3; ++step) {
        if (tid < 384) {
            float acc = b_ih[tid] + b_hh[tid];
            const float* wi = &w_ih[tid * 192];
#pragma unroll 8
            for (int k = 0; k < 192; ++k) acc = fmaf(qs[k], wi[k], acc);
            const float* wh = &w_hh[tid * 96];
#pragma unroll 8
            for (int k = 0; k < 96; ++k) acc = fmaf(h[k], wh[k], acc);
            gates[tid] = acc;
        }
        __syncthreads();
        if (tid < 96) {
            float ig = 1.f / (1.f + __expf(-gates[tid]));
            float fg = 1.f / (1.f + __expf(-gates[96 + tid]));
            float gg = tanhf(gates[192 + tid]);
            float og = 1.f / (1.f + __expf(-gates[288 + tid]));
            float cn = fg * c[tid] + ig * gg;
            c[tid] = cn;
            h[tid] = og * tanhf(cn);
        }
        __syncthreads();
        float pmax = -INFINITY;
        for (int n = s + tid; n < t; n += 512) {
            const float* xr = &xc[n * 96];
            float acc = 0.f;
#pragma unroll 8
            for (int k = 0; k < 96; ++k) acc = fmaf(xr[k], h[k], acc);
            e_ws[n] = acc;
            pmax = fmaxf(pmax, acc);
        }
#pragma unroll
        for (int off = 32; off > 0; off >>= 1) pmax = fmaxf(pmax, __shfl_down(pmax, off));
        if (lane == 0) redm[wid] = pmax;
        __syncthreads();
        if (tid == 0) {
            float m = redm[0];
#pragma unroll
            for (int i = 1; i < 8; ++i) m = fmaxf(m, redm[i]);
            if (!isfinite(m)) m = 0.f;
            sh_scal[0] = m;
        }
        __syncthreads();
        const float emax = sh_scal[0];
        float pa = 0.f;
        for (int n = s + tid; n < t; n += 512) {
            float a = __expf(e_ws[n] - emax);
            e_ws[n] = a;
            pa += a;
        }
#pragma unroll
        for (int off = 32; off > 0; off >>= 1) pa += __shfl_down(pa, off);
        if (lane == 0) reds[wid] = pa;
        __syncthreads();
        if (tid == 0) {
            float a2 = 0.f;
#pragma unroll
            for (int i = 0; i < 8; ++i) a2 += reds[i];
            sh_scal[1] = (a2 > 0.f) ? 1.f / a2 : 0.f;
        }
        __syncthreads();
        const int g = tid / 96, q = tid - g * 96;
        if (tid < 480) {
            float racc = 0.f;
            for (int n = s + g; n < t; n += 5)
                racc = fmaf(e_ws[n], xc[n * 96 + q], racc);
            racc_s[g][q] = racc;
        }
        __syncthreads();
        if (tid < 96) {
            float r = (racc_s[0][tid] + racc_s[1][tid] + racc_s[2][tid]
                     + racc_s[3][tid] + racc_s[4][tid]) * sh_scal[1];
            qs[tid] = h[tid];
            qs[96 + tid] = r;
        }
        __syncthreads();
    }
    if (tid < 192) qs_g[b * 192 + tid] = qs[tid];
}

// -------------------------------- xg = qs@s2s_w^T+b ; pre_m1 = relu(xg@m1^T+b)
__global__ __launch_bounds__(128) void k_xg(const float* __restrict__ qs_g,
        const float* __restrict__ sw, const float* __restrict__ sb,
        const float* __restrict__ m1w, const float* __restrict__ m1b,
        float* __restrict__ pre, float* __restrict__ gsum, float* __restrict__ gsumsq) {
    __shared__ float xg0[96];
    const int tid = threadIdx.x;
    const int b = blockIdx.x;
    if (tid < 96) {
        const float* q = &qs_g[b * 192];
        float acc = sb[tid];
        const float* w = &sw[tid * 192];
#pragma unroll 8
        for (int k = 0; k < 192; ++k) acc = fmaf(q[k], w[k], acc);
        xg0[tid] = acc;
    }
    __syncthreads();
    if (tid < 96) {
        float acc = m1b[tid];
        const float* w = &m1w[tid * 96];
#pragma unroll 8
        for (int k = 0; k < 96; ++k) acc = fmaf(xg0[k], w[k], acc);
        float r = fmaxf(acc, 0.f);
        pre[b * 96 + tid] = r;
        atomicAdd(&gsum[tid], r);
        atomicAdd(&gsumsq[tid], r * r);
    }
}

// ----------------------------------------- tail: BN(m1) -> m2 linear+relu+BN
__global__ __launch_bounds__(256) void k_tail(const float* __restrict__ pre,
        const float* __restrict__ gsum, const float* __restrict__ gsumsq,
        const float* __restrict__ g1, const float* __restrict__ beta1,
        const float* __restrict__ m2w, const float* __restrict__ m2b,
        const float* __restrict__ g2, const float* __restrict__ beta2,
        float* __restrict__ out) {
    __shared__ float xg1[100][97];
    __shared__ float pre2[200];
    __shared__ float ab2[4];
    const int tid = threadIdx.x;
    if (tid < 96) {
        const float invN = 1.f / NG;
        float mean = gsum[tid] * invN;
        float var = fmaxf(gsumsq[tid] * invN - mean * mean, 0.f);
        float a = g1[tid] * rsqrtf(var + EPS);
        float bb = beta1[tid] - mean * a;
        for (int n = 0; n < NG; ++n)
            xg1[n][tid] = fmaf(a, pre[n * 96 + tid], bb);
    }
    __syncthreads();
    if (tid < 200) {
        int n = tid >> 1, cc = tid & 1;
        float acc = m2b[cc];
        const float* w = &m2w[cc * 96];
#pragma unroll 8
        for (int k = 0; k < 96; ++k) acc = fmaf(xg1[n][k], w[k], acc);
        pre2[tid] = fmaxf(acc, 0.f);
    }
    __syncthreads();
    if (tid < 2) {
        float s = 0.f, ss = 0.f;
        for (int n = 0; n < NG; ++n) { float v = pre2[n * 2 + tid]; s += v; ss = fmaf(v, v, ss); }
        const float invN = 1.f / NG;
        float mean = s * invN;
        float var = fmaxf(ss * invN - mean * mean, 0.f);
        float a = g2[tid] * rsqrtf(var + EPS);
        ab2[tid] = a;
        ab2[2 + tid] = beta2[tid] - mean * a;
    }
    __syncthreads();
    if (tid < 200) {
        int cc = tid & 1;
        out[tid] = fmaf(ab2[cc], pre2[tid], ab2[2 + cc]);
    }
}

extern "C" void kernel_launch(void* const* d_in, const int* in_sizes, int n_in,
                              void* d_out, int out_size, void* d_ws, size_t ws_size,
                              hipStream_t stream) {
    (void)in_sizes; (void)n_in; (void)out_size; (void)ws_size;
    const float* x       = (const float*)d_in[0];
    const float* ea      = (const float*)d_in[1];
    const float* c1w     = (const float*)d_in[2];
    const float* c1b     = (const float*)d_in[3];
    const float* c1g     = (const float*)d_in[4];
    const float* c1beta  = (const float*)d_in[5];
    const float* c1root  = (const float*)d_in[6];
    const float* c1bias  = (const float*)d_in[7];
    const float* c2w     = (const float*)d_in[8];
    const float* c2b     = (const float*)d_in[9];
    const float* c2g     = (const float*)d_in[10];
    const float* c2beta  = (const float*)d_in[11];
    const float* c2root  = (const float*)d_in[12];
    const float* c2bias  = (const float*)d_in[13];
    const float* lin1w   = (const float*)d_in[14];
    const float* lin1b   = (const float*)d_in[15];
    const float* lin1g   = (const float*)d_in[16];
    const float* lin1bt  = (const float*)d_in[17];
    const float* wih     = (const float*)d_in[18];
    const float* whh     = (const float*)d_in[19];
    const float* bih     = (const float*)d_in[20];
    const float* bhh     = (const float*)d_in[21];
    const float* s2sw    = (const float*)d_in[22];
    const float* s2sb    = (const float*)d_in[23];
    const float* m1w     = (const float*)d_in[24];
    const float* m1b     = (const float*)d_in[25];
    const float* m1g     = (const float*)d_in[26];
    const float* m1beta  = (const float*)d_in[27];
    const float* m2w     = (const float*)d_in[28];
    const float* m2b     = (const float*)d_in[29];
    const float* m2g     = (const float*)d_in[30];
    const float* m2beta  = (const float*)d_in[31];
    const int* src       = (const int*)d_in[32];
    const int* dst       = (const int*)d_in[33];
    const int* batch     = (const int*)d_in[34];

    float* ws = (float*)d_ws;
    float* stats  = ws;                 // 4096
    float* AB     = ws + 4096;          // 4096: A1|B1|A2|B2
    float* linst  = ws + 8192;          // 192
    float* m1st   = ws + 8384;          // 192
    float* x1     = ws + 8704;          // 320000
    float* x2     = x1 + 320000;        // 320000
    float* prelin = x2 + 320000;        // 960000 (BN in-place -> xc)
    float* e_ws   = prelin + 960000;    // 10000
    float* qs_g   = e_ws + 10000;       // 19200
    float* prem1  = qs_g + 19200;       // 9600

    hipMemsetAsync(ws, 0, 8576 * sizeof(float), stream);

    // ---- fused BN stats for both convs (float2-paired cols, LDS-staged ea)
    k_stats4<<<1250, 512, 0, stream>>>(ea, c1w, c1b, c2w, c2b, stats);

    // ---- conv1 (root1 also computes both convs' BN affines in its last block)
    k_root<<<1251, 256, 0, stream>>>(x, c1root, c1bias, x1,
                                     1, stats, c1g, c1beta, c2g, c2beta, AB);
    k_conv<<<2000, 256, 0, stream>>>(x, ea, src, dst, c1w, c1b, AB, AB + 1024, x1);

    // ---- conv2
    k_root<<<1250, 256, 0, stream>>>(x1, c2root, c2bias, x2,
                                     0, stats, c1g, c1beta, c2g, c2beta, AB);
    k_conv<<<2000, 256, 0, stream>>>(x1, ea, src, dst, c2w, c2b, AB + 2048, AB + 3072, x2);

    // ---- lin1 (Linear+ReLU+BN)
    k_lin1a<<<500, 384, 0, stream>>>(x1, x2, lin1w, lin1b, prelin, linst, linst + 96);
    k_lin1b<<<500, 384, 0, stream>>>(linst, linst + 96, lin1g, lin1bt, prelin, prelin);

    // ---- Set2Set (graph ranges found in-kernel)
    k_s2s<<<100, 512, 0, stream>>>(prelin, batch, wih, whh, bih, bhh, qs_g, e_ws);

    // ---- tail MLPs
    k_xg<<<100, 128, 0, stream>>>(qs_g, s2sw, s2sb, m1w, m1b, prem1, m1st, m1st + 96);
    k_tail<<<1, 256, 0, stream>>>(prem1, m1st, m1st + 96, m1g, m1beta,
                                  m2w, m2b, m2g, m2beta, (float*)d_out);
}

// Round 13
// 282.279 us; speedup vs baseline: 1.8464x; 1.1297x over previous
//
#include <hip/hip_runtime.h>
#include <math.h>

#define NN 10000       // N_NODES
#define NE 160000      // N_EDGES
#define NG 100         // N_GRAPHS
#define DD 32
#define QQ 96
#define EPS 1e-5f

// ---------------- fused BN stats for BOTH convs' edge-MLPs (R9 version, kept).
__global__ __launch_bounds__(512) void k_stats4(const float* __restrict__ ea,
        const float* __restrict__ w1, const float* __restrict__ b1,
        const float* __restrict__ w2, const float* __restrict__ b2,
        float* __restrict__ stats) {
    __shared__ float eas[1536];   // 256 edges x 6 attrs
    const int tid = threadIdx.x;
    const int chunk = blockIdx.x >> 1;
    const int ct = ((blockIdx.x & 1) << 9) | tid;   // column 0..1023
    const float* wr1 = w1 + ct * 6;
    const float* wr2 = w2 + ct * 6;
    float2 W0 = make_float2(wr1[0], wr2[0]);
    float2 W1 = make_float2(wr1[1], wr2[1]);
    float2 W2 = make_float2(wr1[2], wr2[2]);
    float2 W3 = make_float2(wr1[3], wr2[3]);
    float2 W4 = make_float2(wr1[4], wr2[4]);
    float2 W5 = make_float2(wr1[5], wr2[5]);
    float2 Bb = make_float2(b1[ct], b2[ct]);
    float2 S = make_float2(0.f, 0.f), SS = make_float2(0.f, 0.f);
    const int base = chunk * 1536;
    eas[tid]        = ea[base + tid];
    eas[tid + 512]  = ea[base + tid + 512];
    eas[tid + 1024] = ea[base + tid + 1024];
    __syncthreads();
#pragma unroll 4
    for (int el = 0; el < 256; ++el) {
        const float* ep = &eas[el * 6];           // wave-uniform -> broadcast
        float2 p0 = *reinterpret_cast<const float2*>(ep);
        float2 p1 = *reinterpret_cast<const float2*>(ep + 2);
        float2 p2 = *reinterpret_cast<const float2*>(ep + 4);
        float2 y = Bb;
        y.x = fmaf(p0.x, W0.x, y.x); y.y = fmaf(p0.x, W0.y, y.y);
        y.x = fmaf(p0.y, W1.x, y.x); y.y = fmaf(p0.y, W1.y, y.y);
        y.x = fmaf(p1.x, W2.x, y.x); y.y = fmaf(p1.x, W2.y, y.y);
        y.x = fmaf(p1.y, W3.x, y.x); y.y = fmaf(p1.y, W3.y, y.y);
        y.x = fmaf(p2.x, W4.x, y.x); y.y = fmaf(p2.x, W4.y, y.y);
        y.x = fmaf(p2.y, W5.x, y.x); y.y = fmaf(p2.y, W5.y, y.y);
        float rx = fmaxf(y.x, 0.f), ry = fmaxf(y.y, 0.f);
        S.x += rx; S.y += ry;
        SS.x = fmaf(rx, rx, SS.x); SS.y = fmaf(ry, ry, SS.y);
    }
    atomicAdd(&stats[ct], S.x);
    atomicAdd(&stats[1024 + ct], SS.x);
    atomicAdd(&stats[2048 + ct], S.y);
    atomicAdd(&stats[3072 + ct], SS.y);
}

// -------- k_root: out[n,o] = bias[o] + x[n]@root.  Block gridDim-1 (when
// doFin!=0) instead builds BOTH convs' packed per-column records:
// wpack[cv*12288 + col*12 + {0..5:w, 6:bias, 7:A, 8:B}] (48B-aligned stride).
__global__ __launch_bounds__(256) void k_root(const float* __restrict__ x,
        const float* __restrict__ root, const float* __restrict__ bias,
        float* __restrict__ out,
        int doFin, const float* __restrict__ stats,
        const float* __restrict__ g1, const float* __restrict__ beta1,
        const float* __restrict__ g2, const float* __restrict__ beta2,
        const float* __restrict__ nw1, const float* __restrict__ nb1,
        const float* __restrict__ nw2, const float* __restrict__ nb2,
        float* __restrict__ wpack) {
    const int tid = threadIdx.x;
    if (doFin && blockIdx.x == gridDim.x - 1) {
        const float invE = 1.f / NE;
        for (int j = tid; j < 2048; j += 256) {
            int cv = j >> 10, col = j & 1023;
            const float* st = stats + cv * 2048;
            const float* g = cv ? g2 : g1;
            const float* bt = cv ? beta2 : beta1;
            const float* w = (cv ? nw2 : nw1) + col * 6;
            const float* nb = cv ? nb2 : nb1;
            float mean = st[col] * invE;
            float var = fmaxf(st[1024 + col] * invE - mean * mean, 0.f);
            float a = g[col] * rsqrtf(var + EPS);
            float b = bt[col] - mean * a;
            float* rec = wpack + cv * 12288 + col * 12;
            rec[0] = w[0]; rec[1] = w[1]; rec[2] = w[2];
            rec[3] = w[3]; rec[4] = w[4]; rec[5] = w[5];
            rec[6] = nb[col]; rec[7] = a; rec[8] = b;
        }
        return;
    }
    __shared__ float rlds[1024];
#pragma unroll
    for (int r = 0; r < 4; ++r) rlds[tid + 256 * r] = root[tid + 256 * r];
    __syncthreads();
    const int o = tid & 31;
    const int gg = tid >> 5;
    const int n = blockIdx.x * 8 + gg;
    if (n >= NN) return;
    const int half = tid & 32;
    float xs = x[n * 32 + o];
    float acc = bias[o];
#pragma unroll
    for (int i = 0; i < 32; ++i) {
        float xi = __shfl(xs, half | i);
        acc = fmaf(xi, rlds[i * 32 + o], acc);
    }
    out[n * 32 + o] = acc;
}

// ------------- NNConv v6: R12 phase structure (2000 blocks x 80 edges, chunks
// of 16, LDS cross-wave combine -> 32 atomics/edge), but weights come from
// PACKED 48B records: the inevitable per-edge remat (allocator cap ~28 VGPR,
// R3-R12) is now 3 aligned dwordx4 per col instead of ~5 scattered loads.
#define CACCP(PTR, XK, M) { \
    float4 _wa = *reinterpret_cast<const float4*>(PTR); \
    float4 _wb = *reinterpret_cast<const float4*>((PTR) + 4); \
    float _bv = (PTR)[8]; \
    float _y = _wb.z; \
    _y = fmaf(e0, _wa.x, _y); _y = fmaf(e1, _wa.y, _y); _y = fmaf(e2, _wa.z, _y); \
    _y = fmaf(e3, _wa.w, _y); _y = fmaf(e4, _wb.x, _y); _y = fmaf(e5, _wb.y, _y); \
    float _t = fmaf(_wb.w, fmaxf(_y, 0.f), _bv); M = fmaf(XK, _t, M); }

__global__ __launch_bounds__(256) void k_conv(const float* __restrict__ xin,
        const float* __restrict__ ea, const int* __restrict__ src, const int* __restrict__ dst,
        const float* __restrict__ wp, float* __restrict__ agg) {
    __shared__ float part[4][16][32];   // 8 KB
    const int tid = threadIdx.x;
    const int lane = tid & 63;
    const int w = tid >> 6;        // wave = i-quarter (i = 8w .. 8w+7)
    const int p = lane >> 5;
    const int o = lane & 31;

    // this lane's 4 column records (cols j = ((8w + 2K + p)<<5) | o)
    const float* r0 = wp + (((((w << 3) + 0 + p) << 5) | o) * 12);
    const float* r1 = wp + (((((w << 3) + 2 + p) << 5) | o) * 12);
    const float* r2 = wp + (((((w << 3) + 4 + p) << 5) | o) * 12);
    const float* r3 = wp + (((((w << 3) + 6 + p) << 5) | o) * 12);

    const int base0 = blockIdx.x * 80;   // 2000 blocks * 80 edges = NE
#pragma unroll 1
    for (int ch = 0; ch < 5; ++ch) {
        const int base = base0 + ch * 16;
        // ---- phase A: per-wave i-quarter partials for 16 edges (pipelined)
#pragma unroll 4
        for (int m = 0; m < 16; ++m) {
            const int e = base + m;
            const int sc = src[e];                 // block-uniform -> s_load
            const float* er = ea + e * 6;
            float e0 = er[0], e1 = er[1], e2 = er[2], e3 = er[3], e4 = er[4], e5 = er[5];
            const float* xr = xin + sc * 32 + (w << 3);
            float4 qa = *reinterpret_cast<const float4*>(xr);
            float4 qb = *reinterpret_cast<const float4*>(xr + 4);
            float xA = p ? qa.y : qa.x, xB = p ? qa.w : qa.z;
            float xC = p ? qb.y : qb.x, xD = p ? qb.w : qb.z;
            float msg = 0.f;
            CACCP(r0, xA, msg) CACCP(r1, xB, msg) CACCP(r2, xC, msg) CACCP(r3, xD, msg)
            msg += __shfl_xor(msg, 32, 64);
            if (p == 0) part[w][m][o] = msg;
        }
        __syncthreads();
        // ---- phase B: cross-wave sum + one 32-lane atomic per edge (2 edges/thread)
        {
            const int m = tid >> 5;                // 0..7
            const int e = base + m;
            const int dd = dst[e];
            float sum = part[0][m][o] + part[1][m][o] + part[2][m][o] + part[3][m][o];
            atomicAdd(&agg[dd * 32 + o], sum);
            const int m2 = m + 8;
            const int e2 = base + m2;
            const int dd2 = dst[e2];
            float sum2 = part[0][m2][o] + part[1][m2][o] + part[2][m2][o] + part[3][m2][o];
            atomicAdd(&agg[dd2 * 32 + o], sum2);
        }
        __syncthreads();
    }
}

// ---------------------------------------- lin1: relu(cat(x1,x2)@W^T+b) + stats
// (BN affine is applied inline by k_s2s; pre holds the RAW relu output.)
__global__ __launch_bounds__(384) void k_lin1a(const float* __restrict__ x1,
        const float* __restrict__ x2, const float* __restrict__ lw, const float* __restrict__ lb,
        float* __restrict__ pre, float* __restrict__ gsum, float* __restrict__ gsumsq) {
    __shared__ float cat[4][64];
    __shared__ float sh_s[96], sh_ss[96];
    const int tid = threadIdx.x;
    const int np = tid / 96;   // 0..3
    const int q = tid - np * 96;
    float w[64];
#pragma unroll
    for (int k = 0; k < 64; ++k) w[k] = lw[q * 64 + k];
    const float bq = lb[q];
    float s = 0.f, ss = 0.f;
    for (int nb = blockIdx.x * 4; nb < NN; nb += gridDim.x * 4) {
        __syncthreads();
        if (tid < 256) {
            int n2 = tid >> 6, k = tid & 63;
            cat[n2][k] = (k < 32) ? x1[(nb + n2) * 32 + k] : x2[(nb + n2) * 32 + (k - 32)];
        }
        __syncthreads();
        float v = bq;
#pragma unroll
        for (int k = 0; k < 64; ++k) v = fmaf(cat[np][k], w[k], v);
        float r = fmaxf(v, 0.f);
        pre[(nb + np) * 96 + q] = r;
        s += r; ss = fmaf(r, r, ss);
    }
    __syncthreads();
    if (tid < 96) { sh_s[tid] = 0.f; sh_ss[tid] = 0.f; }
    __syncthreads();
    atomicAdd(&sh_s[q], s);
    atomicAdd(&sh_ss[q], ss);
    __syncthreads();
    if (tid < 96) {
        atomicAdd(&gsum[tid], sh_s[tid]);
        atomicAdd(&gsumsq[tid], sh_ss[tid]);
    }
}

// ------------------------------------------------- Set2Set with inline lin1-BN:
// xc = a*pre + b (a,b from lin1 stats). Logits: e = sum_k pre*hA[k] + hb where
// hA = a.*h, hb = sum b.*h. Readout: r_q = a_q*(sum p^ pre) + b_q (sum p^ = 1).
__global__ __launch_bounds__(512) void k_s2s(const float* __restrict__ pre,
        const int* __restrict__ batch,
        const float* __restrict__ gsum, const float* __restrict__ gsumsq,
        const float* __restrict__ lg, const float* __restrict__ lbeta,
        const float* __restrict__ w_ih, const float* __restrict__ w_hh,
        const float* __restrict__ b_ih, const float* __restrict__ b_hh,
        float* __restrict__ qs_g, float* __restrict__ e_ws) {
    __shared__ float qs[192], h[96], c[96], gates[384];
    __shared__ float ab_a[96], ab_b[96], hA[96], bh[96];
    __shared__ float redm[8], reds[8];
    __shared__ float racc_s[5][96];
    __shared__ float sh_scal[3];   // [0]=emax, [1]=1/asum, [2]=hb
    __shared__ int sse[2];
    const int tid = threadIdx.x;
    const int wid = tid >> 6, lane = tid & 63;
    const int b = blockIdx.x;
    if (tid < 2) {   // inline graph-range binary search
        int key = b + tid, lo = 0, hi = NN;
        while (lo < hi) { int mid = (lo + hi) >> 1; if (batch[mid] < key) lo = mid + 1; else hi = mid; }
        sse[tid] = lo;
    }
    if (tid < 192) qs[tid] = 0.f;
    if (tid < 96) {
        h[tid] = 0.f; c[tid] = 0.f;
        const float invN = 1.f / NN;
        float mean = gsum[tid] * invN;
        float var = fmaxf(gsumsq[tid] * invN - mean * mean, 0.f);
        float a = lg[tid] * rsqrtf(var + EPS);
        ab_a[tid] = a;
        ab_b[tid] = lbeta[tid] - mean * a;
    }
    __syncthreads();
    const int s = sse[0], t = sse[1];
    for (int step = 0; step < 3; ++step) {
        if (tid < 384) {
            float acc = b_ih[tid] + b_hh[tid];
            const float* wi = &w_ih[tid * 192];
#pragma unroll 8
            for (int k = 0; k < 192; ++k) acc = fmaf(qs[k], wi[k], acc);
            const float* wh = &w_hh[tid * 96];
#pragma unroll 8
            for (int k = 0; k < 96; ++k) acc = fmaf(h[k], wh[k], acc);
            gates[tid] = acc;
        }
        __syncthreads();
        if (tid < 96) {
            float ig = 1.f / (1.f + __expf(-gates[tid]));
            float fg = 1.f / (1.f + __expf(-gates[96 + tid]));
            float gg = tanhf(gates[192 + tid]);
            float og = 1.f / (1.f + __expf(-gates[288 + tid]));
            float cn = fg * c[tid] + ig * gg;
            c[tid] = cn;
            float hn = og * tanhf(cn);
            h[tid] = hn;
            hA[tid] = ab_a[tid] * hn;
            bh[tid] = ab_b[tid] * hn;
        }
        __syncthreads();
        if (tid < 64) {   // hb = sum_k b_k h_k
            float v = bh[tid] + (tid < 32 ? bh[64 + tid] : 0.f);
#pragma unroll
            for (int off = 32; off > 0; off >>= 1) v += __shfl_down(v, off);
            if (tid == 0) sh_scal[2] = v;
        }
        __syncthreads();
        const float hb = sh_scal[2];
        float pmax = -INFINITY;
        for (int n = s + tid; n < t; n += 512) {
            const float* xr = &pre[n * 96];
            float acc = hb;
#pragma unroll 8
            for (int k = 0; k < 96; ++k) acc = fmaf(xr[k], hA[k], acc);
            e_ws[n] = acc;
            pmax = fmaxf(pmax, acc);
        }
#pragma unroll
        for (int off = 32; off > 0; off >>= 1) pmax = fmaxf(pmax, __shfl_down(pmax, off));
        if (lane == 0) redm[wid] = pmax;
        __syncthreads();
        if (tid == 0) {
            float m = redm[0];
#pragma unroll
            for (int i = 1; i < 8; ++i) m = fmaxf(m, redm[i]);
            if (!isfinite(m)) m = 0.f;
            sh_scal[0] = m;
        }
        __syncthreads();
        const float emax = sh_scal[0];
        float pa = 0.f;
        for (int n = s + tid; n < t; n += 512) {
            float a = __expf(e_ws[n] - emax);
            e_ws[n] = a;
            pa += a;
        }
#pragma unroll
        for (int off = 32; off > 0; off >>= 1) pa += __shfl_down(pa, off);
        if (lane == 0) reds[wid] = pa;
        __syncthreads();
        if (tid == 0) {
            float a2 = 0.f;
#pragma unroll
            for (int i = 0; i < 8; ++i) a2 += reds[i];
            sh_scal[1] = (a2 > 0.f) ? 1.f / a2 : 0.f;
        }
        __syncthreads();
        const int g = tid / 96, q = tid - g * 96;
        if (tid < 480) {
            float racc = 0.f;
            for (int n = s + g; n < t; n += 5)
                racc = fmaf(e_ws[n], pre[n * 96 + q], racc);
            racc_s[g][q] = racc;
        }
        __syncthreads();
        if (tid < 96) {
            float inv = sh_scal[1];
            float racc5 = racc_s[0][tid] + racc_s[1][tid] + racc_s[2][tid]
                        + racc_s[3][tid] + racc_s[4][tid];
            float rq = (inv > 0.f) ? fmaf(ab_a[tid], racc5 * inv, ab_b[tid]) : 0.f;
            qs[tid] = h[tid];
            qs[96 + tid] = rq;
        }
        __syncthreads();
    }
    if (tid < 192) qs_g[b * 192 + tid] = qs[tid];
}

// -------------------------------- xg = qs@s2s_w^T+b ; pre_m1 = relu(xg@m1^T+b)
__global__ __launch_bounds__(128) void k_xg(const float* __restrict__ qs_g,
        const float* __restrict__ sw, const float* __restrict__ sb,
        const float* __restrict__ m1w, const float* __restrict__ m1b,
        float* __restrict__ pre, float* __restrict__ gsum, float* __restrict__ gsumsq) {
    __shared__ float xg0[96];
    const int tid = threadIdx.x;
    const int b = blockIdx.x;
    if (tid < 96) {
        const float* q = &qs_g[b * 192];
        float acc = sb[tid];
        const float* w = &sw[tid * 192];
#pragma unroll 8
        for (int k = 0; k < 192; ++k) acc = fmaf(q[k], w[k], acc);
        xg0[tid] = acc;
    }
    __syncthreads();
    if (tid < 96) {
        float acc = m1b[tid];
        const float* w = &m1w[tid * 96];
#pragma unroll 8
        for (int k = 0; k < 96; ++k) acc = fmaf(xg0[k], w[k], acc);
        float r = fmaxf(acc, 0.f);
        pre[b * 96 + tid] = r;
        atomicAdd(&gsum[tid], r);
        atomicAdd(&gsumsq[tid], r * r);
    }
}

// ----------------------------------------- tail: BN(m1) -> m2 linear+relu+BN
__global__ __launch_bounds__(256) void k_tail(const float* __restrict__ pre,
        const float* __restrict__ gsum, const float* __restrict__ gsumsq,
        const float* __restrict__ g1, const float* __restrict__ beta1,
        const float* __restrict__ m2w, const float* __restrict__ m2b,
        const float* __restrict__ g2, const float* __restrict__ beta2,
        float* __restrict__ out) {
    __shared__ float xg1[100][97];
    __shared__ float pre2[200];
    __shared__ float ab2[4];
    const int tid = threadIdx.x;
    if (tid < 96) {
        const float invN = 1.f / NG;
        float mean = gsum[tid] * invN;
        float var = fmaxf(gsumsq[tid] * invN - mean * mean, 0.f);
        float a = g1[tid] * rsqrtf(var + EPS);
        float bb = beta1[tid] - mean * a;
        for (int n = 0; n < NG; ++n)
            xg1[n][tid] = fmaf(a, pre[n * 96 + tid], bb);
    }
    __syncthreads();
    if (tid < 200) {
        int n = tid >> 1, cc = tid & 1;
        float acc = m2b[cc];
        const float* w = &m2w[cc * 96];
#pragma unroll 8
        for (int k = 0; k < 96; ++k) acc = fmaf(xg1[n][k], w[k], acc);
        pre2[tid] = fmaxf(acc, 0.f);
    }
    __syncthreads();
    if (tid < 2) {
        float s = 0.f, ss = 0.f;
        for (int n = 0; n < NG; ++n) { float v = pre2[n * 2 + tid]; s += v; ss = fmaf(v, v, ss); }
        const float invN = 1.f / NG;
        float mean = s * invN;
        float var = fmaxf(ss * invN - mean * mean, 0.f);
        float a = g2[tid] * rsqrtf(var + EPS);
        ab2[tid] = a;
        ab2[2 + tid] = beta2[tid] - mean * a;
    }
    __syncthreads();
    if (tid < 200) {
        int cc = tid & 1;
        out[tid] = fmaf(ab2[cc], pre2[tid], ab2[2 + cc]);
    }
}

extern "C" void kernel_launch(void* const* d_in, const int* in_sizes, int n_in,
                              void* d_out, int out_size, void* d_ws, size_t ws_size,
                              hipStream_t stream) {
    (void)in_sizes; (void)n_in; (void)out_size; (void)ws_size;
    const float* x       = (const float*)d_in[0];
    const float* ea      = (const float*)d_in[1];
    const float* c1w     = (const float*)d_in[2];
    const float* c1b     = (const float*)d_in[3];
    const float* c1g     = (const float*)d_in[4];
    const float* c1beta  = (const float*)d_in[5];
    const float* c1root  = (const float*)d_in[6];
    const float* c1bias  = (const float*)d_in[7];
    const float* c2w     = (const float*)d_in[8];
    const float* c2b     = (const float*)d_in[9];
    const float* c2g     = (const float*)d_in[10];
    const float* c2beta  = (const float*)d_in[11];
    const float* c2root  = (const float*)d_in[12];
    const float* c2bias  = (const float*)d_in[13];
    const float* lin1w   = (const float*)d_in[14];
    const float* lin1b   = (const float*)d_in[15];
    const float* lin1g   = (const float*)d_in[16];
    const float* lin1bt  = (const float*)d_in[17];
    const float* wih     = (const float*)d_in[18];
    const float* whh     = (const float*)d_in[19];
    const float* bih     = (const float*)d_in[20];
    const float* bhh     = (const float*)d_in[21];
    const float* s2sw    = (const float*)d_in[22];
    const float* s2sb    = (const float*)d_in[23];
    const float* m1w     = (const float*)d_in[24];
    const float* m1b     = (const float*)d_in[25];
    const float* m1g     = (const float*)d_in[26];
    const float* m1beta  = (const float*)d_in[27];
    const float* m2w     = (const float*)d_in[28];
    const float* m2b     = (const float*)d_in[29];
    const float* m2g     = (const float*)d_in[30];
    const float* m2beta  = (const float*)d_in[31];
    const int* src       = (const int*)d_in[32];
    const int* dst       = (const int*)d_in[33];
    const int* batch     = (const int*)d_in[34];

    float* ws = (float*)d_ws;
    float* stats  = ws;                 // 4096
    float* AB     = ws + 4096;          // 4096 (unused legacy slot)
    float* linst  = ws + 8192;          // 192
    float* m1st   = ws + 8384;          // 192
    float* wpack  = ws + 8704;          // 24576: 2 convs x 1024 cols x 12
    float* x1     = wpack + 24576;      // 320000
    float* x2     = x1 + 320000;        // 320000
    float* prelin = x2 + 320000;        // 960000 (raw relu; BN inline in s2s)
    float* e_ws   = prelin + 960000;    // 10000
    float* qs_g   = e_ws + 10000;       // 19200
    float* prem1  = qs_g + 19200;       // 9600
    (void)AB;

    hipMemsetAsync(ws, 0, 8576 * sizeof(float), stream);

    // ---- fused BN stats for both convs (float2-paired cols, LDS-staged ea)
    k_stats4<<<1250, 512, 0, stream>>>(ea, c1w, c1b, c2w, c2b, stats);

    // ---- conv1 (root1's last block builds both convs' packed weight records)
    k_root<<<1251, 256, 0, stream>>>(x, c1root, c1bias, x1,
                                     1, stats, c1g, c1beta, c2g, c2beta,
                                     c1w, c1b, c2w, c2b, wpack);
    k_conv<<<2000, 256, 0, stream>>>(x, ea, src, dst, wpack, x1);

    // ---- conv2
    k_root<<<1250, 256, 0, stream>>>(x1, c2root, c2bias, x2,
                                     0, stats, c1g, c1beta, c2g, c2beta,
                                     c1w, c1b, c2w, c2b, wpack);
    k_conv<<<2000, 256, 0, stream>>>(x1, ea, src, dst, wpack + 12288, x2);

    // ---- lin1 (Linear+ReLU; BN stats only — affine applied inside s2s)
    k_lin1a<<<500, 384, 0, stream>>>(x1, x2, lin1w, lin1b, prelin, linst, linst + 96);

    // ---- Set2Set (graph ranges found in-kernel; lin1 BN inline)
    k_s2s<<<100, 512, 0, stream>>>(prelin, batch, linst, linst + 96, lin1g, lin1bt,
                                   wih, whh, bih, bhh, qs_g, e_ws);

    // ---- tail MLPs
    k_xg<<<100, 128, 0, stream>>>(qs_g, s2sw, s2sb, m1w, m1b, prem1, m1st, m1st + 96);
    k_tail<<<1, 256, 0, stream>>>(prem1, m1st, m1st + 96, m1g, m1beta,
                                  m2w, m2b, m2g, m2beta, (float*)d_out);
}